// Round 1
// baseline (17324.437 us; speedup 1.0000x reference)
//
#include <hip/hip_runtime.h>
#include <hip/hip_cooperative_groups.h>

namespace cg = cooperative_groups;

#define TT 256
#define BB 64
#define DD 1024
#define HH 1024
#define KTOT 2048                 // D + H
#define NWG 256                   // workgroups (16 gate-cols each)
#define BH (BB * HH)              // 65536
#define TBH ((size_t)TT * BB * HH)

typedef short bf16x8 __attribute__((ext_vector_type(8)));
typedef float floatx4 __attribute__((ext_vector_type(4)));

__device__ __forceinline__ unsigned short f2bf(float f) {
  union { float f; unsigned u; } v; v.f = f;
  unsigned r = v.u + 0x7FFFu + ((v.u >> 16) & 1u);   // RNE
  return (unsigned short)(r >> 16);
}

__device__ __forceinline__ float sigmoid_(float x) { return 1.f / (1.f + __expf(-x)); }

__global__ void cvt_x_kernel(const float* __restrict__ x, unsigned short* __restrict__ xb, int n) {
  int i = (blockIdx.x * blockDim.x + threadIdx.x) * 4;
  int stride = gridDim.x * blockDim.x * 4;
  for (; i < n; i += stride) {
    float4 f = *(const float4*)(x + i);
    ushort4 u;
    u.x = f2bf(f.x); u.y = f2bf(f.y); u.z = f2bf(f.z); u.w = f2bf(f.w);
    *(ushort4*)(xb + i) = u;
  }
}

// Persistent cooperative LSTM. Each wg owns 4 h-columns (16 gate-columns:
// n = gate*4 + hc). Weights for those 16 columns (full K=2048) live in LDS
// as bf16, XOR-swizzled so B-fragment ds_read_b128 is conflict-free.
__global__ void __launch_bounds__(256, 1)
lstm_persistent(const float* __restrict__ x,
                const float* __restrict__ Wf, const float* __restrict__ bfp,
                const float* __restrict__ Wi, const float* __restrict__ bip,
                const float* __restrict__ Wg, const float* __restrict__ bgp,
                const float* __restrict__ Wo, const float* __restrict__ bop,
                float* __restrict__ out,
                unsigned short* __restrict__ hb,   // [2][B][H] bf16 double buffer
                float* __restrict__ cb,            // [B][H] fp32 cell state
                const unsigned short* __restrict__ xbf,
                int use_xbf)
{
  extern __shared__ unsigned short wlds[];   // 16 * 2048 bf16 = 64 KB
  const int tid  = threadIdx.x;
  const int wg   = blockIdx.x;
  const int lane = tid & 63;
  const int wave = tid >> 6;      // 0..3 -> 16 batch rows each
  const int quad = lane >> 4;     // 0..3
  const int lcol = lane & 15;     // MFMA m (A) / n (B,C)
  const int gate = lcol >> 2;     // 0=f 1=i 2=g 3=o
  const int hc   = lcol & 3;      // local h column

  // ---- stage 16 weight columns into LDS (bf16, XOR swizzle on 8-elem k-blocks)
  {
    int k = tid * 8;  // 256 threads * 8 = 2048 k per column
    #pragma unroll
    for (int i = 0; i < 16; ++i) {
      int g = i >> 2;
      const float* W = (g == 0) ? Wf : (g == 1) ? Wi : (g == 2) ? Wg : Wo;
      const float* src = W + (size_t)(wg * 4 + (i & 3)) * KTOT + k;
      float4 f0 = *(const float4*)src;
      float4 f1 = *(const float4*)(src + 4);
      bf16x8 wv;
      wv[0]=(short)f2bf(f0.x); wv[1]=(short)f2bf(f0.y); wv[2]=(short)f2bf(f0.z); wv[3]=(short)f2bf(f0.w);
      wv[4]=(short)f2bf(f1.x); wv[5]=(short)f2bf(f1.y); wv[6]=(short)f2bf(f1.z); wv[7]=(short)f2bf(f1.w);
      *(bf16x8*)&wlds[i * KTOT + (k ^ ((i & 7) * 8))] = wv;
    }
  }

  // ---- zero h buffer 0 and c (65536 threads total, one elem each)
  {
    int gid = wg * 256 + tid;
    hb[gid] = 0;        // first 65536 ushorts = h buffer 0
    cb[gid] = 0.f;
  }

  const int m_row = wave * 16 + lcol;                 // batch row for A fragment
  const float* bsel = (gate == 0) ? bfp : (gate == 1) ? bip : (gate == 2) ? bgp : bop;
  const float bias = bsel[wg * 4 + hc];
  const int row_e = wave * 16 + quad * 4;             // C row base (batch)
  const int col_e = wg * 4 + hc;                      // global h column
  const int kq = quad * 8;

  cg::grid_group grid = cg::this_grid();
  __threadfence();
  grid.sync();   // weights staged + h0/c0 zeroed everywhere

  for (int t = 0; t < TT; ++t) {
    floatx4 acc = {0.f, 0.f, 0.f, 0.f};
    const unsigned short* hrow  = hb + (t & 1) * BH + m_row * HH;
    const float* xrow           = x   + ((size_t)t * BB + m_row) * DD;
    const unsigned short* xbrow = xbf + ((size_t)t * BB + m_row) * DD;

    if (use_xbf) {
      #pragma unroll 8
      for (int ks = 0; ks < 32; ++ks) {               // x half of K
        int koff = ks * 32 + kq;
        bf16x8 a = *(const bf16x8*)(xbrow + koff);
        bf16x8 b = *(const bf16x8*)&wlds[lcol * KTOT + (koff ^ ((lcol & 7) * 8))];
        acc = __builtin_amdgcn_mfma_f32_16x16x32_bf16(a, b, acc, 0, 0, 0);
      }
    } else {
      #pragma unroll 8
      for (int ks = 0; ks < 32; ++ks) {               // x half, fp32 loads
        int koff = ks * 32 + kq;
        float4 f0 = *(const float4*)(xrow + koff);
        float4 f1 = *(const float4*)(xrow + koff + 4);
        bf16x8 a;
        a[0]=(short)f2bf(f0.x); a[1]=(short)f2bf(f0.y); a[2]=(short)f2bf(f0.z); a[3]=(short)f2bf(f0.w);
        a[4]=(short)f2bf(f1.x); a[5]=(short)f2bf(f1.y); a[6]=(short)f2bf(f1.z); a[7]=(short)f2bf(f1.w);
        bf16x8 b = *(const bf16x8*)&wlds[lcol * KTOT + (koff ^ ((lcol & 7) * 8))];
        acc = __builtin_amdgcn_mfma_f32_16x16x32_bf16(a, b, acc, 0, 0, 0);
      }
    }
    #pragma unroll 8
    for (int ks = 32; ks < 64; ++ks) {                // h half of K
      int koff = ks * 32 + kq;
      bf16x8 a = *(const bf16x8*)(hrow + (koff - DD));
      bf16x8 b = *(const bf16x8*)&wlds[lcol * KTOT + (koff ^ ((lcol & 7) * 8))];
      acc = __builtin_amdgcn_mfma_f32_16x16x32_bf16(a, b, acc, 0, 0, 0);
    }

    // ---- gates: z(gate,hc) sits at lane quad*16 + gate*4 + hc; combine via shuffles
    unsigned short* hnext = hb + ((t + 1) & 1) * BH;
    #pragma unroll
    for (int r = 0; r < 4; ++r) {
      float v   = acc[r] + bias;
      float v4  = __shfl_xor(v, 4);    // gate^1
      float v8  = __shfl_xor(v, 8);    // gate^2
      float v12 = __shfl_xor(v, 12);   // gate^3
      if (gate == 0) {                 // lanes with gate==0 finalize this (row, hc)
        int row = row_e + r;
        float fv = sigmoid_(v);
        float iv = sigmoid_(v4);
        float gv = tanhf(v8);
        float ov = sigmoid_(v12);
        int idx = row * HH + col_e;
        float cn = fv * cb[idx] + iv * gv;
        float hn = ov * tanhf(cn);
        cb[idx] = cn;
        hnext[idx] = f2bf(hn);
        out[(size_t)t * BH + idx] = hn;
        if (t == TT - 1) {
          out[TBH + idx] = hn;         // hx
          out[TBH + BH + idx] = cn;    // cx
        }
      }
    }
    __threadfence();
    grid.sync();
  }
}

extern "C" void kernel_launch(void* const* d_in, const int* in_sizes, int n_in,
                              void* d_out, int out_size, void* d_ws, size_t ws_size,
                              hipStream_t stream) {
  (void)in_sizes; (void)n_in; (void)out_size;
  const float* x   = (const float*)d_in[0];
  const float* Wf  = (const float*)d_in[1];
  const float* bfp = (const float*)d_in[2];
  const float* Wi  = (const float*)d_in[3];
  const float* bip = (const float*)d_in[4];
  const float* Wg  = (const float*)d_in[5];
  const float* bgp = (const float*)d_in[6];
  const float* Wo  = (const float*)d_in[7];
  const float* bop = (const float*)d_in[8];
  float* out = (float*)d_out;

  unsigned short* hb  = (unsigned short*)d_ws;                    // 256 KB
  float* cb           = (float*)((char*)d_ws + 262144);           // 256 KB
  unsigned short* xbf = (unsigned short*)((char*)d_ws + 524288);  // 32 MB (optional)

  size_t need = 524288 + (size_t)TT * BB * DD * 2;
  int use_xbf = (ws_size >= need) ? 1 : 0;
  if (use_xbf) {
    cvt_x_kernel<<<1024, 256, 0, stream>>>(x, xbf, TT * BB * DD);
  }

  void* args[] = { (void*)&x, (void*)&Wf, (void*)&bfp, (void*)&Wi, (void*)&bip,
                   (void*)&Wg, (void*)&bgp, (void*)&Wo, (void*)&bop,
                   (void*)&out, (void*)&hb, (void*)&cb, (void*)&xbf, (void*)&use_xbf };
  hipLaunchCooperativeKernel((void*)lstm_persistent, dim3(NWG), dim3(256),
                             args, 65536, stream);
}

// Round 2
// 4396.625 us; speedup vs baseline: 3.9404x; 3.9404x over previous
//
#include <hip/hip_runtime.h>
#include <hip/hip_cooperative_groups.h>

namespace cg = cooperative_groups;

#define TT 256
#define BB 64
#define DD 1024
#define HH 1024
#define KTOT 2048                 // D + H
#define NWG 256                   // workgroups (16 gate-cols each)
#define BH (BB * HH)              // 65536
#define TBH ((size_t)TT * BB * HH)

typedef short bf16x8 __attribute__((ext_vector_type(8)));
typedef float floatx4 __attribute__((ext_vector_type(4)));

__device__ __forceinline__ unsigned short f2bf(float f) {
  union { float f; unsigned u; } v; v.f = f;
  unsigned r = v.u + 0x7FFFu + ((v.u >> 16) & 1u);   // RNE
  return (unsigned short)(r >> 16);
}

__device__ __forceinline__ float sigmoid_(float x) { return 1.f / (1.f + __expf(-x)); }

__global__ void cvt_x_kernel(const float* __restrict__ x, unsigned short* __restrict__ xb, int n) {
  int i = (blockIdx.x * blockDim.x + threadIdx.x) * 4;
  int stride = gridDim.x * blockDim.x * 4;
  for (; i < n; i += stride) {
    float4 f = *(const float4*)(x + i);
    ushort4 u;
    u.x = f2bf(f.x); u.y = f2bf(f.y); u.z = f2bf(f.z); u.w = f2bf(f.w);
    *(ushort4*)(xb + i) = u;
  }
}

// Persistent cooperative LSTM. Each wg owns 4 h-columns (16 gate-columns).
// Weights live in LDS (bf16, XOR-swizzled). Cross-wg h exchange via a
// lightweight flag barrier with scoped agent fences (thread 0 only):
// release(wbl2) -> flag store -> spin -> acquire(inv). c state in registers.
__global__ void __launch_bounds__(256, 1)
lstm_persistent(const float* __restrict__ x,
                const float* __restrict__ Wf, const float* __restrict__ bfp,
                const float* __restrict__ Wi, const float* __restrict__ bip,
                const float* __restrict__ Wg, const float* __restrict__ bgp,
                const float* __restrict__ Wo, const float* __restrict__ bop,
                float* __restrict__ out,
                unsigned short* __restrict__ hb,   // [2][B][H] bf16 double buffer
                int* __restrict__ flags,           // [NWG] stride 16 ints (64B)
                const unsigned short* __restrict__ xbf,
                int use_xbf)
{
  extern __shared__ unsigned short wlds[];   // 16 * 2048 bf16 = 64 KB
  const int tid  = threadIdx.x;
  const int wg   = blockIdx.x;
  const int lane = tid & 63;
  const int wave = tid >> 6;      // 0..3 -> 16 batch rows each
  const int quad = lane >> 4;     // 0..3
  const int lcol = lane & 15;     // MFMA m (A) / n (B,C)
  const int gate = lcol >> 2;     // 0=f 1=i 2=g 3=o
  const int hc   = lcol & 3;      // local h column

  // ---- stage 16 weight columns into LDS (bf16, XOR swizzle on 8-elem k-blocks)
  {
    int k = tid * 8;  // 256 threads * 8 = 2048 k per column
    #pragma unroll
    for (int i = 0; i < 16; ++i) {
      int g = i >> 2;
      const float* W = (g == 0) ? Wf : (g == 1) ? Wi : (g == 2) ? Wg : Wo;
      const float* src = W + (size_t)(wg * 4 + (i & 3)) * KTOT + k;
      float4 f0 = *(const float4*)src;
      float4 f1 = *(const float4*)(src + 4);
      bf16x8 wv;
      wv[0]=(short)f2bf(f0.x); wv[1]=(short)f2bf(f0.y); wv[2]=(short)f2bf(f0.z); wv[3]=(short)f2bf(f0.w);
      wv[4]=(short)f2bf(f1.x); wv[5]=(short)f2bf(f1.y); wv[6]=(short)f2bf(f1.z); wv[7]=(short)f2bf(f1.w);
      *(bf16x8*)&wlds[i * KTOT + (k ^ ((i & 7) * 8))] = wv;
    }
  }

  // ---- zero h buffer 0 (65536 threads, one ushort each) and own flag
  {
    int gid = wg * 256 + tid;
    hb[gid] = 0;
    if (tid == 0) flags[wg * 16] = 0;
  }

  const int m_row = wave * 16 + lcol;                 // batch row for A fragment
  const float* bsel = (gate == 0) ? bfp : (gate == 1) ? bip : (gate == 2) ? bgp : bop;
  const float bias = bsel[wg * 4 + hc];
  const int row_e = wave * 16 + quad * 4;             // C row base (batch)
  const int col_e = wg * 4 + hc;                      // global h column
  const int kq = quad * 8;

  float creg[4] = {0.f, 0.f, 0.f, 0.f};               // cell state, wg-private

  cg::grid_group grid = cg::this_grid();
  grid.sync();   // once: weights staged + h0 + flags zeroed everywhere

  for (int t = 0; t < TT; ++t) {
    floatx4 acc = {0.f, 0.f, 0.f, 0.f};
    const unsigned short* hrow  = hb + (t & 1) * BH + m_row * HH;
    const float* xrow           = x   + ((size_t)t * BB + m_row) * DD;
    const unsigned short* xbrow = xbf + ((size_t)t * BB + m_row) * DD;

    if (use_xbf) {
      #pragma unroll 8
      for (int ks = 0; ks < 32; ++ks) {               // x half of K
        int koff = ks * 32 + kq;
        bf16x8 a = *(const bf16x8*)(xbrow + koff);
        bf16x8 b = *(const bf16x8*)&wlds[lcol * KTOT + (koff ^ ((lcol & 7) * 8))];
        acc = __builtin_amdgcn_mfma_f32_16x16x32_bf16(a, b, acc, 0, 0, 0);
      }
    } else {
      #pragma unroll 8
      for (int ks = 0; ks < 32; ++ks) {               // x half, fp32 loads
        int koff = ks * 32 + kq;
        float4 f0 = *(const float4*)(xrow + koff);
        float4 f1 = *(const float4*)(xrow + koff + 4);
        bf16x8 a;
        a[0]=(short)f2bf(f0.x); a[1]=(short)f2bf(f0.y); a[2]=(short)f2bf(f0.z); a[3]=(short)f2bf(f0.w);
        a[4]=(short)f2bf(f1.x); a[5]=(short)f2bf(f1.y); a[6]=(short)f2bf(f1.z); a[7]=(short)f2bf(f1.w);
        bf16x8 b = *(const bf16x8*)&wlds[lcol * KTOT + (koff ^ ((lcol & 7) * 8))];
        acc = __builtin_amdgcn_mfma_f32_16x16x32_bf16(a, b, acc, 0, 0, 0);
      }
    }
    #pragma unroll 8
    for (int ks = 32; ks < 64; ++ks) {                // h half of K
      int koff = ks * 32 + kq;
      bf16x8 a = *(const bf16x8*)(hrow + (koff - DD));
      bf16x8 b = *(const bf16x8*)&wlds[lcol * KTOT + (koff ^ ((lcol & 7) * 8))];
      acc = __builtin_amdgcn_mfma_f32_16x16x32_bf16(a, b, acc, 0, 0, 0);
    }

    // ---- gates: z(gate,hc) at lane quad*16 + gate*4 + hc; combine via shuffles
    unsigned short* hnext = hb + ((t + 1) & 1) * BH;
    #pragma unroll
    for (int r = 0; r < 4; ++r) {
      float v   = acc[r] + bias;
      float v4  = __shfl_xor(v, 4);    // gate^1
      float v8  = __shfl_xor(v, 8);    // gate^2
      float v12 = __shfl_xor(v, 12);   // gate^3
      if (gate == 0) {                 // lanes with gate==0 finalize (row, hc)
        int row = row_e + r;
        float fv = sigmoid_(v);
        float iv = sigmoid_(v4);
        float gv = tanhf(v8);
        float ov = sigmoid_(v12);
        int idx = row * HH + col_e;
        float cn = fv * creg[r] + iv * gv;
        float hn = ov * tanhf(cn);
        creg[r] = cn;
        hnext[idx] = f2bf(hn);
        out[(size_t)t * BH + idx] = hn;
        if (t == TT - 1) {
          out[TBH + idx] = hn;         // hx
          out[TBH + BH + idx] = cn;    // cx
        }
      }
    }

    // ---- lightweight grid barrier (skip after last step)
    if (t < TT - 1) {
      __syncthreads();   // drains each wave's stores to L2 (vmcnt 0 + barrier)
      if (tid == 0) {
        __builtin_amdgcn_fence(__ATOMIC_RELEASE, "agent");   // wbl2: h -> LLC
        __hip_atomic_store(&flags[wg * 16], t + 1,
                           __ATOMIC_RELAXED, __HIP_MEMORY_SCOPE_AGENT);
      }
      if (tid < 64) {                  // wave 0 spins on all 256 flags
        int j0 = tid, j1 = tid + 64, j2 = tid + 128, j3 = tid + 192;
        while (true) {
          int a = __hip_atomic_load(&flags[j0 * 16], __ATOMIC_RELAXED, __HIP_MEMORY_SCOPE_AGENT);
          int b = __hip_atomic_load(&flags[j1 * 16], __ATOMIC_RELAXED, __HIP_MEMORY_SCOPE_AGENT);
          int c = __hip_atomic_load(&flags[j2 * 16], __ATOMIC_RELAXED, __HIP_MEMORY_SCOPE_AGENT);
          int d = __hip_atomic_load(&flags[j3 * 16], __ATOMIC_RELAXED, __HIP_MEMORY_SCOPE_AGENT);
          bool ok = (a > t) && (b > t) && (c > t) && (d > t);
          if (__all(ok)) break;
          __builtin_amdgcn_s_sleep(1);
        }
        if (tid == 0)
          __builtin_amdgcn_fence(__ATOMIC_ACQUIRE, "agent"); // inv L1/L2
      }
      __syncthreads();
    }
  }
}

extern "C" void kernel_launch(void* const* d_in, const int* in_sizes, int n_in,
                              void* d_out, int out_size, void* d_ws, size_t ws_size,
                              hipStream_t stream) {
  (void)in_sizes; (void)n_in; (void)out_size;
  const float* x   = (const float*)d_in[0];
  const float* Wf  = (const float*)d_in[1];
  const float* bfp = (const float*)d_in[2];
  const float* Wi  = (const float*)d_in[3];
  const float* bip = (const float*)d_in[4];
  const float* Wg  = (const float*)d_in[5];
  const float* bgp = (const float*)d_in[6];
  const float* Wo  = (const float*)d_in[7];
  const float* bop = (const float*)d_in[8];
  float* out = (float*)d_out;

  unsigned short* hb  = (unsigned short*)d_ws;                    // 256 KB
  int* flags          = (int*)((char*)d_ws + 262144);             // 16 KB
  unsigned short* xbf = (unsigned short*)((char*)d_ws + 524288);  // 32 MB (optional)

  size_t need = 524288 + (size_t)TT * BB * DD * 2;
  int use_xbf = (ws_size >= need) ? 1 : 0;
  if (use_xbf) {
    cvt_x_kernel<<<1024, 256, 0, stream>>>(x, xbf, TT * BB * DD);
  }

  void* args[] = { (void*)&x, (void*)&Wf, (void*)&bfp, (void*)&Wi, (void*)&bip,
                   (void*)&Wg, (void*)&bgp, (void*)&Wo, (void*)&bop,
                   (void*)&out, (void*)&hb, (void*)&flags, (void*)&xbf, (void*)&use_xbf };
  hipLaunchCooperativeKernel((void*)lstm_persistent, dim3(NWG), dim3(256),
                             args, 65536, stream);
}